// Round 1
// baseline (351.592 us; speedup 1.0000x reference)
//
#include <hip/hip_runtime.h>

// SelfAttentionHead: B=4, S=4096, D=1024, Hd=128
// Pipeline: wt (transpose W -> f16) -> proj (x@W MFMA, writes Q,K,V^T f16)
//           -> attn (flash-style fused QK^T/softmax/PV, f32 out)

#define BB 4
#define SS 4096
#define DD 1024
#define HDIM 128

typedef _Float16 f16;
typedef _Float16 half8 __attribute__((ext_vector_type(8)));
typedef float f32x4 __attribute__((ext_vector_type(4)));

__device__ __forceinline__ void gload_lds16(const void* g, void* l) {
  __builtin_amdgcn_global_load_lds(
      (const __attribute__((address_space(1))) void*)g,
      (__attribute__((address_space(3))) void*)l, 16, 0, 0);
}

__device__ __forceinline__ f32x4 mfma16(half8 a, half8 b, f32x4 c) {
  return __builtin_amdgcn_mfma_f32_16x16x32_f16(a, b, c, 0, 0, 0);
}

// ---------------------------------------------------------------------------
// Kernel 1: W [1024][128] f32 (x3) -> Wt_cat [384][1024] f16 (row n = output col)
__global__ void wt_kernel(const float* __restrict__ Wq, const float* __restrict__ Wk,
                          const float* __restrict__ Wv, f16* __restrict__ w3t) {
  const int n = blockIdx.x;  // 0..383
  const float* W = (n < 128) ? Wq : (n < 256) ? Wk : Wv;
  const int col = n & 127;
  for (int d = threadIdx.x; d < DD; d += blockDim.x)
    w3t[(size_t)n * DD + d] = (f16)W[(size_t)d * HDIM + col];
}

// ---------------------------------------------------------------------------
// Kernel 2: projection GEMM. 256 blocks x 256 thr (4 waves, 2x2 wave grid).
// Block = 64 rows of x; wave = 32 rows x 192 cols. MFMA 16x16x32 f16.
// Outputs: Qm,Km [B*S][128] f16; VTm [B][128][S] f16 (transposed V).
__global__ __launch_bounds__(256) void proj_kernel(
    const float* __restrict__ x, const f16* __restrict__ w3t,
    f16* __restrict__ Qm, f16* __restrict__ Km, f16* __restrict__ VTm) {
  const int tid = threadIdx.x;
  const int lane = tid & 63;
  const int wid = tid >> 6;
  const int lo = lane & 15, hi = lane >> 4;
  const int mhalf = wid >> 1, nhalf = wid & 1;
  const int row0 = blockIdx.x * 64 + mhalf * 32;

  f32x4 acc[2][12];
#pragma unroll
  for (int m = 0; m < 2; ++m)
#pragma unroll
    for (int nf = 0; nf < 12; ++nf) acc[m][nf] = (f32x4){0.f, 0.f, 0.f, 0.f};

#pragma unroll 2
  for (int kc = 0; kc < 32; ++kc) {
    const int k0 = kc * 32 + hi * 8;
    half8 af[2];
#pragma unroll
    for (int m = 0; m < 2; ++m) {
      // A-frag: row = l&15, k = (l>>4)*8 + i  (8 contiguous f32 -> f16)
      const float* xp = x + (size_t)(row0 + m * 16 + lo) * DD + k0;
      f32x4 a0 = *(const f32x4*)xp;
      f32x4 a1 = *(const f32x4*)(xp + 4);
      half8 h;
#pragma unroll
      for (int j = 0; j < 4; ++j) { h[j] = (f16)a0[j]; h[j + 4] = (f16)a1[j]; }
      af[m] = h;
    }
#pragma unroll
    for (int nf = 0; nf < 12; ++nf) {
      // B-frag: col = l&15, k = (l>>4)*8 + i ; w3t is [n][k] so 16B contiguous
      const int n = nhalf * 192 + nf * 16 + lo;
      half8 bf = *(const half8*)(w3t + (size_t)n * DD + k0);
      acc[0][nf] = mfma16(af[0], bf, acc[0][nf]);
      acc[1][nf] = mfma16(af[1], bf, acc[1][nf]);
    }
  }

  // Epilogue: C lane map row=(l>>4)*4+r, col=l&15 (m89-verified)
#pragma unroll
  for (int m = 0; m < 2; ++m) {
#pragma unroll
    for (int nf = 0; nf < 12; ++nf) {
      const int n = nhalf * 192 + nf * 16 + lo;
#pragma unroll
      for (int r = 0; r < 4; ++r) {
        const int row = row0 + m * 16 + hi * 4 + r;
        const f16 v = (f16)acc[m][nf][r];
        if (n < 128) {
          Qm[(size_t)row * HDIM + n] = v;
        } else if (n < 256) {
          Km[(size_t)row * HDIM + (n - 128)] = v;
        } else {
          const int b = row >> 12, s = row & 4095;
          VTm[((size_t)b * HDIM + (n - 256)) * SS + s] = v;
        }
      }
    }
  }
}

// ---------------------------------------------------------------------------
// Kernel 3: fused attention. 256 blocks (b, qtile of 64 rows) x 128 thr (2 waves).
// Wave owns 32 Q-rows. KBLK=64. K-tile [64][128] f16, V^T-tile [128][64] f16 in
// LDS, XOR-swizzled (byte ^= (row&7)<<4) via pre-swizzled global_load_lds source.
__global__ __launch_bounds__(128) void attn_kernel(
    const f16* __restrict__ Qm, const f16* __restrict__ Km,
    const f16* __restrict__ VTm, float* __restrict__ out) {
  __shared__ __align__(16) f16 Kt[64 * 128];     // [key][hd], swizzled
  __shared__ __align__(16) f16 Vt[128 * 64];     // [hd][key], swizzled
  __shared__ __align__(16) f16 Pb[2][32 * 64];   // per-wave P, swizzled

  const int b = blockIdx.x >> 6;
  const int qt = blockIdx.x & 63;
  const int wid = threadIdx.x >> 6;
  const int lane = threadIdx.x & 63;
  const int lo = lane & 15, hi = lane >> 4;
  const int q0 = qt * 64 + wid * 32;

  constexpr float SCL2E = 0.12751744560817508f;  // log2(e)/sqrt(128)

  // Q fragments in registers: 32 rows x 128, 2 m-frags x 4 k-chunks
  half8 qf[2][4];
#pragma unroll
  for (int m = 0; m < 2; ++m)
#pragma unroll
    for (int c = 0; c < 4; ++c)
      qf[m][c] = *(const half8*)(Qm + (size_t)(b * SS + q0 + m * 16 + lo) * HDIM +
                                 c * 32 + hi * 8);

  f32x4 of[2][8];
  float mrun[2][4], lrun[2][4];
#pragma unroll
  for (int m = 0; m < 2; ++m) {
#pragma unroll
    for (int g = 0; g < 8; ++g) of[m][g] = (f32x4){0.f, 0.f, 0.f, 0.f};
#pragma unroll
    for (int r = 0; r < 4; ++r) { mrun[m][r] = -1e30f; lrun[m][r] = 0.f; }
  }

  const char* kgb = (const char*)(Km + (size_t)(b * SS) * HDIM);
  const char* vgb = (const char*)(VTm + (size_t)(b * HDIM) * SS);
  char* PbW = (char*)&Pb[wid][0];

  for (int kt = 0; kt < 64; ++kt) {
    // ---- stage K tile (64 rows x 256B): linear LDS dest, inverse-swizzled src
#pragma unroll
    for (int i = 0; i < 8; ++i) {
      const int rbase = wid * 32 + i * 4;
      const int r = rbase + (lane >> 4);
      const int inner = ((lane & 15) * 16) ^ ((r & 7) << 4);
      gload_lds16(kgb + (size_t)(kt * 64 + r) * 256 + inner, (char*)Kt + rbase * 256);
    }
    // ---- stage V^T tile (128 rows x 128B)
#pragma unroll
    for (int i = 0; i < 8; ++i) {
      const int rbase = wid * 64 + i * 8;
      const int r = rbase + (lane >> 3);
      const int inner = ((lane & 7) * 16) ^ ((r & 7) << 4);
      gload_lds16(vgb + (size_t)r * (SS * 2) + (size_t)kt * 128 + inner,
                  (char*)Vt + rbase * 128);
    }
    __syncthreads();  // compiler drains vmcnt before s_barrier

    // ---- QK^T: sc[m][g] = S[q 16m..][key 16g..]
    f32x4 sc[2][4];
#pragma unroll
    for (int m = 0; m < 2; ++m)
#pragma unroll
      for (int g = 0; g < 4; ++g) sc[m][g] = (f32x4){0.f, 0.f, 0.f, 0.f};
#pragma unroll
    for (int c = 0; c < 4; ++c) {
#pragma unroll
      for (int g = 0; g < 4; ++g) {
        const int row = g * 16 + lo;  // key index in tile
        const half8 kb = *(const half8*)((const char*)Kt + row * 256 +
                                         ((c * 64 + hi * 16) ^ ((row & 7) << 4)));
        sc[0][g] = mfma16(qf[0][c], kb, sc[0][g]);
        sc[1][g] = mfma16(qf[1][c], kb, sc[1][g]);
      }
    }

    // ---- online softmax (row q = m*16 + hi*4 + r; keys spread over lo & g)
#pragma unroll
    for (int m = 0; m < 2; ++m) {
#pragma unroll
      for (int r = 0; r < 4; ++r) {
        float tm = fmaxf(fmaxf(sc[m][0][r], sc[m][1][r]),
                         fmaxf(sc[m][2][r], sc[m][3][r])) * SCL2E;
#pragma unroll
        for (int off = 1; off < 16; off <<= 1) tm = fmaxf(tm, __shfl_xor(tm, off, 64));
        const float mnew = fmaxf(mrun[m][r], tm);
        const float alpha = exp2f(mrun[m][r] - mnew);
        float psum = 0.f;
        f16 pv[4];
#pragma unroll
        for (int g = 0; g < 4; ++g) {
          const float p = exp2f(sc[m][g][r] * SCL2E - mnew);
          psum += p;
          pv[g] = (f16)p;
        }
#pragma unroll
        for (int off = 1; off < 16; off <<= 1) psum += __shfl_xor(psum, off, 64);
        lrun[m][r] = lrun[m][r] * alpha + psum;
        mrun[m][r] = mnew;
#pragma unroll
        for (int g2 = 0; g2 < 8; ++g2) of[m][g2][r] *= alpha;
        // scatter P to per-wave LDS (swizzled) for A-frag re-layout
        const int prow = m * 16 + hi * 4 + r;
#pragma unroll
        for (int g = 0; g < 4; ++g)
          *(f16*)(PbW + prow * 128 + (((g * 16 + lo) * 2) ^ ((prow & 7) << 4))) = pv[g];
      }
    }
    asm volatile("s_waitcnt lgkmcnt(0)" ::: "memory");  // P writes visible to reads

    // ---- PV: O += P(32x64) @ V(64x128)
#pragma unroll
    for (int c = 0; c < 2; ++c) {
      half8 pa[2];
#pragma unroll
      for (int m = 0; m < 2; ++m) {
        const int prow = m * 16 + lo;
        pa[m] = *(const half8*)(PbW + prow * 128 +
                                ((c * 64 + hi * 16) ^ ((prow & 7) << 4)));
      }
#pragma unroll
      for (int g2 = 0; g2 < 8; ++g2) {
        const int vrow = g2 * 16 + lo;  // head-dim row of V^T
        const half8 vb = *(const half8*)((const char*)Vt + vrow * 128 +
                                         ((c * 64 + hi * 16) ^ ((vrow & 7) << 4)));
        of[0][g2] = mfma16(pa[0], vb, of[0][g2]);
        of[1][g2] = mfma16(pa[1], vb, of[1][g2]);
      }
    }
    __syncthreads();  // protect Kt/Vt before next stage
  }

  // ---- epilogue: normalize and store f32
  float* op = out + ((size_t)(b * SS + q0)) * HDIM;
#pragma unroll
  for (int m = 0; m < 2; ++m) {
#pragma unroll
    for (int r = 0; r < 4; ++r) {
      const float inv = 1.0f / lrun[m][r];
      const int row = m * 16 + hi * 4 + r;
#pragma unroll
      for (int g2 = 0; g2 < 8; ++g2)
        op[(size_t)row * HDIM + g2 * 16 + lo] = of[m][g2][r] * inv;
    }
  }
}

// ---------------------------------------------------------------------------
extern "C" void kernel_launch(void* const* d_in, const int* in_sizes, int n_in,
                              void* d_out, int out_size, void* d_ws, size_t ws_size,
                              hipStream_t stream) {
  (void)in_sizes; (void)n_in; (void)out_size; (void)ws_size;
  const float* x  = (const float*)d_in[0];
  const float* Wq = (const float*)d_in[1];
  const float* Wk = (const float*)d_in[2];
  const float* Wv = (const float*)d_in[3];
  float* out = (float*)d_out;

  // ws layout (f16): Q[4M B] K[4MB] VT[4MB] Wt[0.75MB]  => ~12.8 MB total
  f16* Qm  = (f16*)d_ws;
  f16* Km  = Qm + (size_t)BB * SS * HDIM;
  f16* VTm = Km + (size_t)BB * SS * HDIM;
  f16* W3  = VTm + (size_t)BB * SS * HDIM;

  hipLaunchKernelGGL(wt_kernel, dim3(384), dim3(256), 0, stream, Wq, Wk, Wv, W3);
  hipLaunchKernelGGL(proj_kernel, dim3(256), dim3(256), 0, stream, x, W3, Qm, Km, VTm);
  hipLaunchKernelGGL(attn_kernel, dim3(256), dim3(128), 0, stream, Qm, Km, VTm, out);
}

// Round 2
// 223.059 us; speedup vs baseline: 1.5762x; 1.5762x over previous
//
#include <hip/hip_runtime.h>

// SelfAttentionHead: B=4, S=4096, D=1024, Hd=128
// Pipeline: wt (transpose W -> f16) -> proj (x@W MFMA, writes Q,K,V^T f16)
//           -> attn (flash-style, dbuf LDS + counted vmcnt pipeline, f32 out)

#define BB 4
#define SS 4096
#define DD 1024
#define HDIM 128

typedef _Float16 f16;
typedef _Float16 half8 __attribute__((ext_vector_type(8)));
typedef float f32x4 __attribute__((ext_vector_type(4)));

__device__ __forceinline__ void gload_lds16(const void* g, void* l) {
  __builtin_amdgcn_global_load_lds(
      (const __attribute__((address_space(1))) void*)g,
      (__attribute__((address_space(3))) void*)l, 16, 0, 0);
}

__device__ __forceinline__ f32x4 mfma16(half8 a, half8 b, f32x4 c) {
  return __builtin_amdgcn_mfma_f32_16x16x32_f16(a, b, c, 0, 0, 0);
}

// ---------------------------------------------------------------------------
// Kernel 1: W [1024][128] f32 (x3) -> Wt_cat [384][1024] f16 (row n = output col)
__global__ void wt_kernel(const float* __restrict__ Wq, const float* __restrict__ Wk,
                          const float* __restrict__ Wv, f16* __restrict__ w3t) {
  const int n = blockIdx.x;  // 0..383
  const float* W = (n < 128) ? Wq : (n < 256) ? Wk : Wv;
  const int col = n & 127;
  for (int d = threadIdx.x; d < DD; d += blockDim.x)
    w3t[(size_t)n * DD + d] = (f16)W[(size_t)d * HDIM + col];
}

// ---------------------------------------------------------------------------
// Kernel 2: projection GEMM. 256 blocks x 256 thr (4 waves, 2x2 wave grid).
__global__ __launch_bounds__(256) void proj_kernel(
    const float* __restrict__ x, const f16* __restrict__ w3t,
    f16* __restrict__ Qm, f16* __restrict__ Km, f16* __restrict__ VTm) {
  const int tid = threadIdx.x;
  const int lane = tid & 63;
  const int wid = tid >> 6;
  const int lo = lane & 15, hi = lane >> 4;
  const int mhalf = wid >> 1, nhalf = wid & 1;
  const int row0 = blockIdx.x * 64 + mhalf * 32;

  f32x4 acc[2][12];
#pragma unroll
  for (int m = 0; m < 2; ++m)
#pragma unroll
    for (int nf = 0; nf < 12; ++nf) acc[m][nf] = (f32x4){0.f, 0.f, 0.f, 0.f};

#pragma unroll 2
  for (int kc = 0; kc < 32; ++kc) {
    const int k0 = kc * 32 + hi * 8;
    half8 af[2];
#pragma unroll
    for (int m = 0; m < 2; ++m) {
      const float* xp = x + (size_t)(row0 + m * 16 + lo) * DD + k0;
      f32x4 a0 = *(const f32x4*)xp;
      f32x4 a1 = *(const f32x4*)(xp + 4);
      half8 h;
#pragma unroll
      for (int j = 0; j < 4; ++j) { h[j] = (f16)a0[j]; h[j + 4] = (f16)a1[j]; }
      af[m] = h;
    }
#pragma unroll
    for (int nf = 0; nf < 12; ++nf) {
      const int n = nhalf * 192 + nf * 16 + lo;
      half8 bf = *(const half8*)(w3t + (size_t)n * DD + k0);
      acc[0][nf] = mfma16(af[0], bf, acc[0][nf]);
      acc[1][nf] = mfma16(af[1], bf, acc[1][nf]);
    }
  }

#pragma unroll
  for (int m = 0; m < 2; ++m) {
#pragma unroll
    for (int nf = 0; nf < 12; ++nf) {
      const int n = nhalf * 192 + nf * 16 + lo;
#pragma unroll
      for (int r = 0; r < 4; ++r) {
        const int row = row0 + m * 16 + hi * 4 + r;
        const f16 v = (f16)acc[m][nf][r];
        if (n < 128) {
          Qm[(size_t)row * HDIM + n] = v;
        } else if (n < 256) {
          Km[(size_t)row * HDIM + (n - 128)] = v;
        } else {
          const int b = row >> 12, s = row & 4095;
          VTm[((size_t)b * HDIM + (n - 256)) * SS + s] = v;
        }
      }
    }
  }
}

// ---------------------------------------------------------------------------
// Kernel 3: fused attention, pipelined.
// 512 blocks (XCD-swizzled) x 128 thr (2 waves). Wave = 16 Q-rows, block = 32.
// KVBLK=64. Double-buffered K[64][128] / V^T[128][64] f16 tiles in LDS,
// XOR-swizzled (byte ^= (row&7)<<4) via pre-swizzled global_load_lds source.
// Raw s_barrier + counted s_waitcnt vmcnt(16): next tile's loads stay in
// flight across the barrier (T3/T4-lite).
__global__ __launch_bounds__(128) void attn_kernel(
    const f16* __restrict__ Qm, const f16* __restrict__ Km,
    const f16* __restrict__ VTm, float* __restrict__ out) {
  __shared__ __align__(16) f16 Kt[2][64 * 128];   // [buf][key][hd], swizzled
  __shared__ __align__(16) f16 Vt[2][128 * 64];   // [buf][hd][key], swizzled
  __shared__ __align__(16) f16 Pb[2][16 * 64];    // per-wave P, swizzled

  // XCD-aware bijective swizzle: 512 blocks, 8 XCDs, 64 contiguous per XCD
  const int lbid = (blockIdx.x & 7) * 64 + (blockIdx.x >> 3);
  const int b = lbid >> 7;
  const int qt = lbid & 127;
  const int wid = threadIdx.x >> 6;
  const int lane = threadIdx.x & 63;
  const int lo = lane & 15, hi = lane >> 4;
  const int q0 = qt * 32 + wid * 16;

  constexpr float SCL2E = 0.12751744560817508f;  // log2(e)/sqrt(128)

  // Q fragments in registers: 16 rows x 128 = 4 k-chunks
  half8 qf[4];
#pragma unroll
  for (int c = 0; c < 4; ++c)
    qf[c] = *(const half8*)(Qm + (size_t)(b * SS + q0 + lo) * HDIM + c * 32 + hi * 8);

  f32x4 of[8];
  float mrun[4], lrun[4];
#pragma unroll
  for (int g = 0; g < 8; ++g) of[g] = (f32x4){0.f, 0.f, 0.f, 0.f};
#pragma unroll
  for (int r = 0; r < 4; ++r) { mrun[r] = -1e30f; lrun[r] = 0.f; }

  const char* kgb = (const char*)(Km + (size_t)(b * SS) * HDIM);
  const char* vgb = (const char*)(VTm + (size_t)(b * HDIM) * SS);
  char* PbW = (char*)&Pb[wid][0];

  // stage tile kt into buffer bufsel: 16 gload_lds16 per thread (8 K + 8 V)
  auto STAGE = [&](int kt, int bufsel) {
    char* kd = (char*)&Kt[bufsel][0];
    char* vd = (char*)&Vt[bufsel][0];
#pragma unroll
    for (int i = 0; i < 8; ++i) {
      const int cid = i * 128 + wid * 64 + lane;           // 16B chunk id 0..1023
      const int r = cid >> 4;                               // key row 0..63
      gload_lds16(kgb + (size_t)(kt * 64 + r) * 256 + (((cid & 15) * 16) ^ ((r & 7) << 4)),
                  kd + (size_t)(i * 128 + wid * 64) * 16);
    }
#pragma unroll
    for (int i = 0; i < 8; ++i) {
      const int cid = i * 128 + wid * 64 + lane;
      const int r = cid >> 3;                               // hd row 0..127
      gload_lds16(vgb + (size_t)r * (SS * 2) + (size_t)kt * 128 + (((cid & 7) * 16) ^ ((r & 7) << 4)),
                  vd + (size_t)(i * 128 + wid * 64) * 16);
    }
  };

  STAGE(0, 0);
  int cur = 0;
  for (int kt = 0; kt < 64; ++kt) {
    if (kt + 1 < 64) {
      STAGE(kt + 1, cur ^ 1);
      asm volatile("s_waitcnt vmcnt(16)" ::: "memory");  // tile kt's 16 loads landed
    } else {
      asm volatile("s_waitcnt vmcnt(0)" ::: "memory");
    }
    __builtin_amdgcn_s_barrier();  // all waves' tile-kt loads visible

    const char* KtC = (const char*)&Kt[cur][0];
    const char* VtC = (const char*)&Vt[cur][0];

    // ---- QK^T: sc[g] = S[q 0..15][key 16g..]
    f32x4 sc[4];
#pragma unroll
    for (int g = 0; g < 4; ++g) sc[g] = (f32x4){0.f, 0.f, 0.f, 0.f};
#pragma unroll
    for (int c = 0; c < 4; ++c) {
#pragma unroll
      for (int g = 0; g < 4; ++g) {
        const int row = g * 16 + lo;  // key index in tile
        const half8 kb = *(const half8*)(KtC + row * 256 +
                                         ((c * 64 + hi * 16) ^ ((row & 7) << 4)));
        sc[g] = mfma16(qf[c], kb, sc[g]);
      }
    }

    // ---- online softmax (row q = hi*4 + r; keys spread over lo & g)
#pragma unroll
    for (int r = 0; r < 4; ++r) {
      float tm = fmaxf(fmaxf(sc[0][r], sc[1][r]),
                       fmaxf(sc[2][r], sc[3][r])) * SCL2E;
#pragma unroll
      for (int off = 1; off < 16; off <<= 1) tm = fmaxf(tm, __shfl_xor(tm, off, 64));
      const float mnew = fmaxf(mrun[r], tm);
      const float alpha = exp2f(mrun[r] - mnew);
      float psum = 0.f;
      f16 pv[4];
#pragma unroll
      for (int g = 0; g < 4; ++g) {
        const float p = exp2f(sc[g][r] * SCL2E - mnew);
        psum += p;
        pv[g] = (f16)p;
      }
#pragma unroll
      for (int off = 1; off < 16; off <<= 1) psum += __shfl_xor(psum, off, 64);
      lrun[r] = lrun[r] * alpha + psum;
      mrun[r] = mnew;
#pragma unroll
      for (int g2 = 0; g2 < 8; ++g2) of[g2][r] *= alpha;
      const int prow = hi * 4 + r;
#pragma unroll
      for (int g = 0; g < 4; ++g)
        *(f16*)(PbW + prow * 128 + (((g * 16 + lo) * 2) ^ ((prow & 7) << 4))) = pv[g];
    }
    asm volatile("s_waitcnt lgkmcnt(0)" ::: "memory");  // P writes visible to reads

    // ---- PV: O += P(16x64) @ V(64x128)
#pragma unroll
    for (int c = 0; c < 2; ++c) {
      const half8 pa = *(const half8*)(PbW + lo * 128 +
                                       ((c * 64 + hi * 16) ^ ((lo & 7) << 4)));
#pragma unroll
      for (int g2 = 0; g2 < 8; ++g2) {
        const int vrow = g2 * 16 + lo;  // head-dim row of V^T
        const half8 vb = *(const half8*)(VtC + vrow * 128 +
                                         ((c * 64 + hi * 16) ^ ((vrow & 7) << 4)));
        of[g2] = mfma16(pa, vb, of[g2]);
      }
    }
    __builtin_amdgcn_s_barrier();  // all waves done reading buf before overwrite
    cur ^= 1;
  }

  // ---- epilogue: normalize and store f32
  float* op = out + ((size_t)(b * SS + q0)) * HDIM;
#pragma unroll
  for (int r = 0; r < 4; ++r) {
    const float inv = 1.0f / lrun[r];
    const int row = hi * 4 + r;
#pragma unroll
    for (int g2 = 0; g2 < 8; ++g2)
      op[(size_t)row * HDIM + g2 * 16 + lo] = of[g2][r] * inv;
  }
}

// ---------------------------------------------------------------------------
extern "C" void kernel_launch(void* const* d_in, const int* in_sizes, int n_in,
                              void* d_out, int out_size, void* d_ws, size_t ws_size,
                              hipStream_t stream) {
  (void)in_sizes; (void)n_in; (void)out_size; (void)ws_size;
  const float* x  = (const float*)d_in[0];
  const float* Wq = (const float*)d_in[1];
  const float* Wk = (const float*)d_in[2];
  const float* Wv = (const float*)d_in[3];
  float* out = (float*)d_out;

  f16* Qm  = (f16*)d_ws;
  f16* Km  = Qm + (size_t)BB * SS * HDIM;
  f16* VTm = Km + (size_t)BB * SS * HDIM;
  f16* W3  = VTm + (size_t)BB * SS * HDIM;

  hipLaunchKernelGGL(wt_kernel, dim3(384), dim3(256), 0, stream, Wq, Wk, Wv, W3);
  hipLaunchKernelGGL(proj_kernel, dim3(256), dim3(256), 0, stream, x, W3, Qm, Km, VTm);
  hipLaunchKernelGGL(attn_kernel, dim3(512), dim3(128), 0, stream, Qm, Km, VTm, out);
}